// Round 1
// baseline (32.379 us; speedup 1.0000x reference)
//
#include <hip/hip_runtime.h>

// CapsNet dynamic routing, fully fused. Key algebraic identity: u = x@W is
// linear in x, so  sum_i c[j,i]*u[j,i,:] = (sum_i c[j,i]*x[i,:]) @ W_j  and
// o[j]·u[j,i,:] = x[i,:]·(W_j @ o[j]).  u (168 MB) is never materialized.
//
// One block per batch element b. 512 threads.
//   Phase A : y[j][k] = sum_i c[i][j] * x[i][k]      (thread = (g=i-chunk, k))
//   Phase S : s[j][d] = sum_k y[j][k] W[k][j*16+d];  squash -> o   (160 thr)
//   Phase WT: wt[k][j] = sum_d W[k][j*16+d] o[j][d]                (320 thr)
//   Phase B : blog[i][j] += sum_k x[i][k] wt[k][j];  softmax_j -> c[i][j]
//             (thread i owns blog row i in registers)
// r=0 special-cased: c = 1/J uniform -> y[j][k] = 0.1 * sum_i x[i][k].

#define NI 512
#define NK 32
#define NJ 10
#define ND 16
#define NT 512
#define WPAD 164   // W row pad: bank stride 4 instead of 0

__global__ __launch_bounds__(NT, 2) void capsnet_kernel(
    const float* __restrict__ x, const float* __restrict__ W,
    float* __restrict__ out)
{
    __shared__ float xT[NK][NI + 1];                       // 65,664 B (pad +1: conflict-free both axes)
    __shared__ float Wl[NK][WPAD];                         // 20,992 B
    __shared__ __attribute__((aligned(16))) float cred[NI * 12]; // 24,576 B: c[i][0..9] rows of 12; reused as reduce scratch
    __shared__ float yb[NJ * 32];                          //  1,280 B
    __shared__ __attribute__((aligned(16))) float ob[NJ * ND];   //    640 B
    __shared__ __attribute__((aligned(16))) float wtT[NK * 12];  //  1,536 B
    __shared__ float lg[NJ];

    const int tid = threadIdx.x;
    const int b   = blockIdx.x;
    const int g   = tid >> 5;   // i-chunk 0..15
    const int k   = tid & 31;   // input-dim lane

    // ---- stage x (transposed) and W into LDS ----
    {
        const float4* xb4 = reinterpret_cast<const float4*>(x + (size_t)b * NI * NK);
        #pragma unroll
        for (int r = 0; r < 8; ++r) {          // 4096 float4 / 512 thr
            const int t4 = tid + r * NT;
            const float4 v = xb4[t4];
            const int flat = t4 << 2;
            const int i  = flat >> 5;
            const int k0 = flat & 31;
            xT[k0 + 0][i] = v.x; xT[k0 + 1][i] = v.y;
            xT[k0 + 2][i] = v.z; xT[k0 + 3][i] = v.w;
        }
        #pragma unroll
        for (int r = 0; r < 10; ++r) {         // 5120 floats / 512 thr
            const int e = tid + r * NT;
            const int row = e / 160;
            Wl[row][e - row * 160] = W[e];
        }
    }
    __syncthreads();

    // ---- register-cache the two x slices this thread ever needs ----
    float xa[32];   // xT[k][g*32 + ii]  (phase A)
    float xr[32];   // xT[kk][tid]       (phase B)
    {
        const int i0 = g << 5;
        #pragma unroll
        for (int ii = 0; ii < 32; ++ii) xa[ii] = xT[k][i0 + ii];
        #pragma unroll
        for (int kk = 0; kk < 32; ++kk) xr[kk] = xT[kk][tid];
    }

    float blog[NJ];   // routing logits, row i = tid, register-resident
    #pragma unroll
    for (int j = 0; j < NJ; ++j) blog[j] = 0.f;

    for (int r = 0; r < 3; ++r) {
        // ===== Phase A =====
        if (r == 0) {
            // c uniform 1/J: y[j][k] = 0.1 * sum_i x[i][k]
            float a = 0.f;
            #pragma unroll
            for (int ii = 0; ii < 32; ++ii) a += xa[ii];
            cred[(g << 5) + k] = a;
            __syncthreads();
            if (tid < 32) {
                float s = 0.f;
                #pragma unroll
                for (int gg = 0; gg < 16; ++gg) s += cred[(gg << 5) + tid];
                s *= 0.1f;
                #pragma unroll
                for (int j = 0; j < NJ; ++j) yb[(j << 5) + tid] = s;
            }
            __syncthreads();
        } else {
            float acc[NJ];
            #pragma unroll
            for (int j = 0; j < NJ; ++j) acc[j] = 0.f;
            const int i0 = g << 5;
            #pragma unroll
            for (int ii = 0; ii < 32; ++ii) {
                const int i = i0 + ii;
                const float xv = xa[ii];
                const float4 c0 = *reinterpret_cast<const float4*>(&cred[i * 12]);
                const float4 c1 = *reinterpret_cast<const float4*>(&cred[i * 12 + 4]);
                const float2 c2 = *reinterpret_cast<const float2*>(&cred[i * 12 + 8]);
                acc[0] = fmaf(c0.x, xv, acc[0]); acc[1] = fmaf(c0.y, xv, acc[1]);
                acc[2] = fmaf(c0.z, xv, acc[2]); acc[3] = fmaf(c0.w, xv, acc[3]);
                acc[4] = fmaf(c1.x, xv, acc[4]); acc[5] = fmaf(c1.y, xv, acc[5]);
                acc[6] = fmaf(c1.z, xv, acc[6]); acc[7] = fmaf(c1.w, xv, acc[7]);
                acc[8] = fmaf(c2.x, xv, acc[8]); acc[9] = fmaf(c2.y, xv, acc[9]);
            }
            __syncthreads();               // all c reads done; cred becomes scratch
            #pragma unroll
            for (int j = 0; j < NJ; ++j) cred[g * 320 + (j << 5) + k] = acc[j];
            __syncthreads();
            if (tid < 320) {
                float s = 0.f;
                #pragma unroll
                for (int gg = 0; gg < 16; ++gg) s += cred[gg * 320 + tid];
                yb[tid] = s;
            }
            __syncthreads();
        }

        // ===== Phase S: s = y @ W_j, squash -> o (r==2: logits) =====
        if (tid < 160) {
            const int j = tid >> 4, d = tid & 15;
            float s = 0.f;
            #pragma unroll
            for (int kk = 0; kk < NK; ++kk)
                s = fmaf(yb[(j << 5) + kk], Wl[kk][(j << 4) + d], s);
            float sq = s * s;
            sq += __shfl_xor(sq, 1); sq += __shfl_xor(sq, 2);
            sq += __shfl_xor(sq, 4); sq += __shfl_xor(sq, 8);
            const float scale = (sq / (1.f + sq)) / sqrtf(sq + 1e-7f);
            const float o_ = s * scale;
            if (r < 2) {
                ob[(j << 4) + d] = o_;
            } else {
                float ss = o_;
                ss += __shfl_xor(ss, 1); ss += __shfl_xor(ss, 2);
                ss += __shfl_xor(ss, 4); ss += __shfl_xor(ss, 8);
                if (d == 0) lg[j] = ss;   // logits[j] = sum_d o[j][d]
            }
        }
        __syncthreads();

        if (r == 2) break;

        // ===== Phase WT: wt[k][j] = W_j-row(k) . o[j] =====
        if (tid < 320) {
            const int j = tid >> 5, kk = tid & 31;
            float s = 0.f;
            #pragma unroll
            for (int d = 0; d < ND; ++d)
                s = fmaf(Wl[kk][(j << 4) + d], ob[(j << 4) + d], s);
            wtT[kk * 12 + j] = s;
        }
        __syncthreads();

        // ===== Phase B: blog row update + softmax_j -> c row =====
        {
            float del[NJ];
            #pragma unroll
            for (int j = 0; j < NJ; ++j) del[j] = 0.f;
            #pragma unroll
            for (int kk = 0; kk < NK; ++kk) {
                const float xv = xr[kk];
                const float4 w0 = *reinterpret_cast<const float4*>(&wtT[kk * 12]);
                const float4 w1 = *reinterpret_cast<const float4*>(&wtT[kk * 12 + 4]);
                const float2 w2 = *reinterpret_cast<const float2*>(&wtT[kk * 12 + 8]);
                del[0] = fmaf(xv, w0.x, del[0]); del[1] = fmaf(xv, w0.y, del[1]);
                del[2] = fmaf(xv, w0.z, del[2]); del[3] = fmaf(xv, w0.w, del[3]);
                del[4] = fmaf(xv, w1.x, del[4]); del[5] = fmaf(xv, w1.y, del[5]);
                del[6] = fmaf(xv, w1.z, del[6]); del[7] = fmaf(xv, w1.w, del[7]);
                del[8] = fmaf(xv, w2.x, del[8]); del[9] = fmaf(xv, w2.y, del[9]);
            }
            float m = -1e30f;
            #pragma unroll
            for (int j = 0; j < NJ; ++j) { blog[j] += del[j]; m = fmaxf(m, blog[j]); }
            float e[NJ]; float sum = 0.f;
            #pragma unroll
            for (int j = 0; j < NJ; ++j) { e[j] = __expf(blog[j] - m); sum += e[j]; }
            const float inv = 1.f / sum;
            #pragma unroll
            for (int j = 0; j < NJ; ++j) cred[tid * 12 + j] = e[j] * inv;
        }
        __syncthreads();
    }

    // ---- final: softmax over J of logits, write out[b][0..9] ----
    if (tid == 0) {
        float m = -1e30f;
        #pragma unroll
        for (int j = 0; j < NJ; ++j) m = fmaxf(m, lg[j]);
        float e[NJ]; float sum = 0.f;
        #pragma unroll
        for (int j = 0; j < NJ; ++j) { e[j] = __expf(lg[j] - m); sum += e[j]; }
        const float inv = 1.f / sum;
        #pragma unroll
        for (int j = 0; j < NJ; ++j) out[b * NJ + j] = e[j] * inv;
    }
}

extern "C" void kernel_launch(void* const* d_in, const int* in_sizes, int n_in,
                              void* d_out, int out_size, void* d_ws, size_t ws_size,
                              hipStream_t stream) {
    (void)in_sizes; (void)n_in; (void)d_ws; (void)ws_size; (void)out_size;
    const float* x = (const float*)d_in[0];
    const float* W = (const float*)d_in[1];
    float* out = (float*)d_out;
    hipLaunchKernelGGL(capsnet_kernel, dim3(512), dim3(NT), 0, stream, x, W, out);
}